// Round 7
// baseline (8892.645 us; speedup 1.0000x reference)
//
#include <hip/hip_runtime.h>
#include <cmath>

typedef unsigned short u16;
typedef unsigned long long u64;
typedef __attribute__((ext_vector_type(4))) float f32x4;
typedef __attribute__((ext_vector_type(8))) __bf16 bf16x8;
typedef unsigned short u16x4 __attribute__((ext_vector_type(4)));
typedef unsigned short u16x8 __attribute__((ext_vector_type(8)));

#define T_STEPS 512
#define NBLK 64
#define FINAL_OFF 33554432u  // 512*64*1024

// ---------------- workspace layout (bytes) ----------------
#define OFF_XR   0ull
#define OFF_XZ   (OFF_XR + 67108864ull)     // 512*64*1024 * 2B each
#define OFF_XH   (OFF_XZ + 67108864ull)
#define OFF_WXRT (OFF_XH + 67108864ull)     // 1024*1024*2B each
#define OFF_WXZT (OFF_WXRT + 2097152ull)
#define OFF_WXHT (OFF_WXZT + 2097152ull)
#define OFF_WHRT (OFF_WXHT + 2097152ull)
#define OFF_WHZT (OFF_WHRT + 2097152ull)
#define OFF_WHHT (OFF_WHZT + 2097152ull)
#define OFF_HBF  (OFF_WHHT + 2097152ull)    // 64*1024 bf16 (cross-block, coherent)
#define OFF_RHBF (OFF_HBF + 131072ull)      // 64*1024 bf16 (cross-block, coherent)
#define OFF_HF32 (OFF_RHBF + 131072ull)     // (unused this version)
#define OFF_BAR  (OFF_HF32 + 262144ull)     // 256 per-wave flags, DENSE 4B stride
#define BAR_BYTES 65600ull

// ---------------- helpers ----------------
__device__ __forceinline__ u16 f2bf(float f) {
    unsigned u = __builtin_bit_cast(unsigned, f);
    unsigned r = (u + 0x7FFFu + ((u >> 16) & 1u)) >> 16;
    return (u16)r;
}
__device__ __forceinline__ float bf2f(u16 h) {
    unsigned u = ((unsigned)h) << 16;
    return __builtin_bit_cast(float, u);
}
#define MFMA16 __builtin_amdgcn_mfma_f32_16x16x32_bf16

// coherent (agent-scope) atomic accesses: flags + cross-block data stores.
__device__ __forceinline__ void sta16(u16* p, u16 v) {
    __hip_atomic_store(p, v, __ATOMIC_RELAXED, __HIP_MEMORY_SCOPE_AGENT);
}
__device__ __forceinline__ void sta32(unsigned* p, unsigned v) {
    __hip_atomic_store(p, v, __ATOMIC_RELAXED, __HIP_MEMORY_SCOPE_AGENT);
}
__device__ __forceinline__ unsigned lda32(const unsigned* p) {
    return __hip_atomic_load(p, __ATOMIC_RELAXED, __HIP_MEMORY_SCOPE_AGENT);
}

// Raw coherent 16B load (sc0|sc1): same visibility as relaxed agent atomic,
// fire-and-forget issue; completion claimed by explicit vmcnt(0)+sched_barrier.
#define LD_A4(dst, vo, base)                                          \
    asm volatile("global_load_dwordx4 %0, %1, %2 sc0 sc1"             \
                 : "=v"(dst) : "v"(vo), "s"(base))

// ---------------- phase 0: transpose + fp32->bf16 convert, [K][N] -> [N][K] ----------------
__global__ __launch_bounds__(256) void transpose_cvt(
    const float* __restrict__ W0, const float* __restrict__ W1, const float* __restrict__ W2,
    const float* __restrict__ W3, const float* __restrict__ W4, const float* __restrict__ W5,
    u16* __restrict__ D0, u16* __restrict__ D1, u16* __restrict__ D2,
    u16* __restrict__ D3, u16* __restrict__ D4, u16* __restrict__ D5)
{
    const float* S[6] = {W0, W1, W2, W3, W4, W5};
    u16* D[6] = {D0, D1, D2, D3, D4, D5};
    int z = blockIdx.z;
    const float* W = S[z];
    u16* Dt = D[z];
    __shared__ float tile[32][33];
    int bx = blockIdx.x * 32, by = blockIdx.y * 32;
    int tx = threadIdx.x & 31, ty = threadIdx.x >> 5;
    for (int i = ty; i < 32; i += 8)
        tile[i][tx] = W[(size_t)(by + i) * 1024 + bx + tx];
    __syncthreads();
    for (int i = ty; i < 32; i += 8)
        Dt[(size_t)(bx + i) * 1024 + by + tx] = f2bf(tile[tx][i]);
}

// ---------------- phase 1: X @ Wx* + b -> bf16 projections ----------------
__global__ __launch_bounds__(256, 2) void proj_gemm(
    const float* __restrict__ X,
    const u16* __restrict__ Wt0, const u16* __restrict__ Wt1, const u16* __restrict__ Wt2,
    const float* __restrict__ b0, const float* __restrict__ b1, const float* __restrict__ b2,
    u16* __restrict__ P0, u16* __restrict__ P1, u16* __restrict__ P2)
{
    int z = blockIdx.z;
    const u16* Wt = (z == 0) ? Wt0 : (z == 1) ? Wt1 : Wt2;
    const float* bias = (z == 0) ? b0 : (z == 1) ? b1 : b2;
    u16* P = (z == 0) ? P0 : (z == 1) ? P1 : P2;

    __shared__ u16 Asm[128][72];
    __shared__ u16 Bsm[128][72];

    int tid = threadIdx.x, lane = tid & 63, w = tid >> 6;
    int m0 = blockIdx.y * 128, n0 = blockIdx.x * 128;
    int mw = (w >> 1) * 64, nw = (w & 1) * 64;
    int l15 = lane & 15, lq = lane >> 4;

    f32x4 zero = {0.f, 0.f, 0.f, 0.f};
    f32x4 acc[4][4];
    #pragma unroll
    for (int mi = 0; mi < 4; ++mi)
        #pragma unroll
        for (int nj = 0; nj < 4; ++nj) acc[mi][nj] = zero;

    for (int k0 = 0; k0 < 1024; k0 += 64) {
        #pragma unroll
        for (int i = 0; i < 8; ++i) {
            int flat = i * 256 + tid;
            int r = flat >> 4, c4 = flat & 15;
            float4 v = *(const float4*)(X + (size_t)(m0 + r) * 1024 + k0 + c4 * 4);
            u16x4 pk = {f2bf(v.x), f2bf(v.y), f2bf(v.z), f2bf(v.w)};
            *(u16x4*)&Asm[r][c4 * 4] = pk;
        }
        #pragma unroll
        for (int i = 0; i < 4; ++i) {
            int flat = i * 256 + tid;
            int n = flat >> 3, seg = flat & 7;
            *(u16x8*)&Bsm[n][seg * 8] = *(const u16x8*)(Wt + (size_t)(n0 + n) * 1024 + k0 + seg * 8);
        }
        __syncthreads();
        #pragma unroll
        for (int kk = 0; kk < 2; ++kk) {
            bf16x8 af[4], bg[4];
            #pragma unroll
            for (int mi = 0; mi < 4; ++mi)
                af[mi] = *(const bf16x8*)&Asm[mw + mi * 16 + l15][kk * 32 + lq * 8];
            #pragma unroll
            for (int nj = 0; nj < 4; ++nj)
                bg[nj] = *(const bf16x8*)&Bsm[nw + nj * 16 + l15][kk * 32 + lq * 8];
            #pragma unroll
            for (int mi = 0; mi < 4; ++mi)
                #pragma unroll
                for (int nj = 0; nj < 4; ++nj)
                    acc[mi][nj] = MFMA16(af[mi], bg[nj], acc[mi][nj], 0, 0, 0);
        }
        __syncthreads();
    }
    #pragma unroll
    for (int mi = 0; mi < 4; ++mi)
        #pragma unroll
        for (int nj = 0; nj < 4; ++nj)
            #pragma unroll
            for (int r = 0; r < 4; ++r) {
                int m = m0 + mw + mi * 16 + lq * 4 + r;
                int n = n0 + nw + nj * 16 + l15;
                float v = acc[mi][nj][r] + bias[n];
                P[(size_t)m * 1024 + n] = f2bf(v);
            }
}

// ---------------- phase 2: persistent recurrent kernel, PER-WAVE dataflow ----------------
// Identical to round 6 EXCEPT flag layout: flags are packed DENSELY, grouped
// by wave index: flag[mi][b] at bar[mi*64 + b] (4B stride). A poll gather
// (lane l -> bar[mi*64 + l]) reads 64 CONSECUTIVE dwords = 256B = 2 cache
// lines => ~2 coherence-point transactions per poll instead of 64 (the old
// 128B-strided layout touched 64 distinct lines). Writers hit disjoint
// dwords with plain UC stores (no RMW -> no round-0 contention). Protocol
// unchanged: init->1; stage1(t)->2t+2; stage2(t)->2t+3; stage1 consumes hbf
// gated >=2t+1; stage2 consumes rhbf gated >=2t+2; per-wave vmcnt(0) drain
// before every publish (release; WAR-safe on single-buffered hbf/rhbf).
__global__ __launch_bounds__(256, 1) void gru_rec(
    const u16* __restrict__ XR, const u16* __restrict__ XZ, const u16* __restrict__ XH,
    const u16* __restrict__ Whrt, const u16* __restrict__ Whzt, const u16* __restrict__ Whht,
    const float* __restrict__ state,
    u16* __restrict__ hbf, u16* __restrict__ rhbf,
    unsigned* __restrict__ bar, float* __restrict__ out)
{
    __shared__ u16 Wsm[48 * 1024];  // rows 0-15 Whr, 16-31 Whz, 32-47 Whh (96 KB)

    const int b = blockIdx.x, tid = threadIdx.x;
    const int lane = tid & 63, mi = tid >> 6;
    const int n15 = lane & 15, q = lane >> 4;
    const int k7 = n15 & 7;
    const int colg = 16 * b + n15;
    const int rowA = mi * 16 + n15;
    const int rot = (((b >> 1) + ((b & 1) << 4)) + mi * 8) & 31;  // per-wave start pair
    const u64 own_bit = 1ull << b;

    // fill LDS weight slices (swizzled 16B chunks: phys = chunk ^ (row&7))
    {
        int r0 = tid >> 3, seg = tid & 7;
        #pragma unroll
        for (int pass = 0; pass < 2; ++pass) {
            int row = pass * 32 + r0;
            if (row < 48) {
                const u16* src = (row < 16) ? (Whrt + (size_t)(16 * b + row) * 1024)
                               : (row < 32) ? (Whzt + (size_t)(16 * b + row - 16) * 1024)
                                            : (Whht + (size_t)(16 * b + row - 32) * 1024);
                #pragma unroll
                for (int v = 0; v < 16; ++v) {
                    int chunk = seg * 16 + v;
                    int phys = chunk ^ (row & 7);
                    *(u16x8*)&Wsm[row * 1024 + phys * 8] = *(const u16x8*)(src + chunk * 8);
                }
            }
        }
    }
    // init h: each wave stores its own tile (rows [16mi,..) x cols [16b,..))
    f32x4 hcar;
    #pragma unroll
    for (int r = 0; r < 4; ++r) {
        int idx = (mi * 16 + q * 4 + r) * 1024 + colg;
        float v = state[idx];
        hcar[r] = v;
        sta16(hbf + idx, f2bf(v));
    }
    // publish init (flag = 1), per-wave; then one barrier for Wsm visibility
    asm volatile("s_waitcnt vmcnt(0)" ::: "memory");
    if (lane == 0) sta32(bar + (unsigned)(mi * 64 + b), 1u);
    __syncthreads();  // Wsm ready for all 4 waves; last sync in the kernel

    const u64 hb64 = (u64)hbf;
    const u64 rb64 = (u64)rhbf;
    const unsigned vbA = (unsigned)(rowA * 2048 + q * 16);  // A-fragment byte base
    // lane l -> block l's wave-mi flag (dense: 64 consecutive dwords per mi)
    const unsigned* fp = bar + (unsigned)(mi * 64 + lane);
    unsigned* myflag = bar + (unsigned)(mi * 64 + b);

    for (int t = 0; t < T_STEPS; ++t) {
        f32x4 zreg;
        // ---------------- stage 1: R,Z; write rhbf = R*h ----------------
        {
            u16 xr16[4], xz16[4];
            #pragma unroll
            for (int r = 0; r < 4; ++r) {
                size_t xoff = (size_t)t * 65536 + (mi * 16 + q * 4 + r) * 1024 + colg;
                xr16[r] = XR[xoff];
                xz16[r] = XZ[xoff];
            }
            // dataflow consume: issue A-load for each k-pair as its producers arrive
            f32x4 a[32];
            const unsigned T1 = 2u * t + 1u;
            u64 rdy = __ballot(lda32(fp) >= T1) | own_bit;  // fast path: one gather
            #pragma unroll
            for (int i = 0; i < 32; ++i) {
                int kb = (i + rot) & 31;
                u64 need = 3ull << (2 * kb);
                while ((rdy & need) != need) {
                    __builtin_amdgcn_s_sleep(1);
                    rdy = __ballot(lda32(fp) >= T1) | own_bit;
                }
                LD_A4(a[i], vbA + kb * 64, hb64);
            }
            asm volatile("s_waitcnt vmcnt(0)" ::: "memory");
            __builtin_amdgcn_sched_barrier(0);

            f32x4 aRa = {0,0,0,0}, aRb = {0,0,0,0}, aZa = {0,0,0,0}, aZb = {0,0,0,0};
            #pragma unroll
            for (int i = 0; i < 32; ++i) {
                int kb = (i + rot) & 31;
                bf16x8 av = __builtin_bit_cast(bf16x8, a[i]);
                int ph = ((kb * 4 + q) ^ k7) * 8;
                bf16x8 br = *(const bf16x8*)&Wsm[n15 * 1024 + ph];
                bf16x8 bz = *(const bf16x8*)&Wsm[(16 + n15) * 1024 + ph];
                if (i & 1) { aRb = MFMA16(av, br, aRb, 0, 0, 0); aZb = MFMA16(av, bz, aZb, 0, 0, 0); }
                else       { aRa = MFMA16(av, br, aRa, 0, 0, 0); aZa = MFMA16(av, bz, aZa, 0, 0, 0); }
            }
            f32x4 accR = aRa + aRb, accZ = aZa + aZb;
            #pragma unroll
            for (int r = 0; r < 4; ++r) {
                int idx = (mi * 16 + q * 4 + r) * 1024 + colg;
                float rpre = accR[r] + bf2f(xr16[r]);
                float zpre = accZ[r] + bf2f(xz16[r]);
                float R = 1.f / (1.f + __expf(-rpre));
                zreg[r] = 1.f / (1.f + __expf(-zpre));
                sta16(rhbf + idx, f2bf(R * hcar[r]));
            }
            // publish stage 1 (flag = 2t+2): per-wave drain + own flag store
            asm volatile("s_waitcnt vmcnt(0)" ::: "memory");
            if (lane == 0) sta32(myflag, 2u * t + 2u);
        }
        // ---------------- stage 2: Hhat = tanh(Xh + (R*h)@Whh); blend ----------------
        {
            u16 xh16[4];
            #pragma unroll
            for (int r = 0; r < 4; ++r) {
                size_t xoff = (size_t)t * 65536 + (mi * 16 + q * 4 + r) * 1024 + colg;
                xh16[r] = XH[xoff];
            }
            f32x4 a[32];
            const unsigned T2 = 2u * t + 2u;
            u64 rdy = __ballot(lda32(fp) >= T2) | own_bit;  // fast path: one gather
            #pragma unroll
            for (int i = 0; i < 32; ++i) {
                int kb = (i + rot) & 31;
                u64 need = 3ull << (2 * kb);
                while ((rdy & need) != need) {
                    __builtin_amdgcn_s_sleep(1);
                    rdy = __ballot(lda32(fp) >= T2) | own_bit;
                }
                LD_A4(a[i], vbA + kb * 64, rb64);
            }
            asm volatile("s_waitcnt vmcnt(0)" ::: "memory");
            __builtin_amdgcn_sched_barrier(0);

            f32x4 ca = {0,0,0,0}, cb = {0,0,0,0};
            #pragma unroll
            for (int i = 0; i < 32; ++i) {
                int kb = (i + rot) & 31;
                bf16x8 av = __builtin_bit_cast(bf16x8, a[i]);
                int ph = ((kb * 4 + q) ^ k7) * 8;
                bf16x8 bh = *(const bf16x8*)&Wsm[(32 + n15) * 1024 + ph];
                if (i & 1) cb = MFMA16(av, bh, cb, 0, 0, 0);
                else       ca = MFMA16(av, bh, ca, 0, 0, 0);
            }
            f32x4 acc = ca + cb;
            float hn4[4];
            #pragma unroll
            for (int r = 0; r < 4; ++r) {
                int idx = (mi * 16 + q * 4 + r) * 1024 + colg;
                float pre = acc[r] + bf2f(xh16[r]);
                float ax = fabsf(pre);
                float e = __expf(-2.f * ax);
                float th = (1.f - e) / (1.f + e);
                float hh = (pre < 0.f) ? -th : th;
                float hn = zreg[r] * hcar[r] + (1.f - zreg[r]) * hh;
                hn4[r] = hn;
                hcar[r] = hn;
                sta16(hbf + idx, f2bf(hn));     // shared (coherent)
            }
            if (t != T_STEPS - 1) {
                // publish stage 2 (flag = 2t+3) BEFORE the out stores (out is
                // write-once, consumed only at kernel end; keeps HBM stores
                // off the publish critical path)
                asm volatile("s_waitcnt vmcnt(0)" ::: "memory");
                if (lane == 0) sta32(myflag, 2u * t + 3u);
            }
            #pragma unroll
            for (int r = 0; r < 4; ++r) {
                int idx = (mi * 16 + q * 4 + r) * 1024 + colg;
                size_t xoff = (size_t)t * 65536 + idx;
                out[xoff] = hn4[r];
                if (t == T_STEPS - 1) out[FINAL_OFF + idx] = hn4[r];
            }
        }
    }
}

// ---------------- launch ----------------
extern "C" void kernel_launch(void* const* d_in, const int* in_sizes, int n_in,
                              void* d_out, int out_size, void* d_ws, size_t ws_size,
                              hipStream_t stream) {
    (void)in_sizes; (void)n_in; (void)out_size; (void)ws_size;
    const float* X     = (const float*)d_in[0];
    const float* state = (const float*)d_in[1];
    const float* Wxr   = (const float*)d_in[2];
    const float* Whr   = (const float*)d_in[3];
    const float* br    = (const float*)d_in[4];
    const float* Wxz   = (const float*)d_in[5];
    const float* Whz   = (const float*)d_in[6];
    const float* bz    = (const float*)d_in[7];
    const float* Wxh   = (const float*)d_in[8];
    const float* Whh   = (const float*)d_in[9];
    const float* bh    = (const float*)d_in[10];
    float* out = (float*)d_out;
    char* ws = (char*)d_ws;

    u16* XR   = (u16*)(ws + OFF_XR);
    u16* XZ   = (u16*)(ws + OFF_XZ);
    u16* XH   = (u16*)(ws + OFF_XH);
    u16* WXRT = (u16*)(ws + OFF_WXRT);
    u16* WXZT = (u16*)(ws + OFF_WXZT);
    u16* WXHT = (u16*)(ws + OFF_WXHT);
    u16* WHRT = (u16*)(ws + OFF_WHRT);
    u16* WHZT = (u16*)(ws + OFF_WHZT);
    u16* WHHT = (u16*)(ws + OFF_WHHT);
    u16* HBF  = (u16*)(ws + OFF_HBF);
    u16* RHBF = (u16*)(ws + OFF_RHBF);
    unsigned* BAR = (unsigned*)(ws + OFF_BAR);

    hipMemsetAsync(BAR, 0, BAR_BYTES, stream);

    transpose_cvt<<<dim3(32, 32, 6), 256, 0, stream>>>(
        Wxr, Wxz, Wxh, Whr, Whz, Whh,
        WXRT, WXZT, WXHT, WHRT, WHZT, WHHT);

    proj_gemm<<<dim3(8, 256, 3), 256, 0, stream>>>(
        X, WXRT, WXZT, WXHT, br, bz, bh, XR, XZ, XH);

    gru_rec<<<dim3(NBLK), 256, 0, stream>>>(
        XR, XZ, XH, WHRT, WHZT, WHHT, state,
        HBF, RHBF, BAR, out);
}

// Round 8
// 5776.739 us; speedup vs baseline: 1.5394x; 1.5394x over previous
//
#include <hip/hip_runtime.h>
#include <cmath>

typedef unsigned short u16;
typedef unsigned long long u64;
typedef __attribute__((ext_vector_type(4))) float f32x4;
typedef __attribute__((ext_vector_type(8))) __bf16 bf16x8;
typedef unsigned short u16x4 __attribute__((ext_vector_type(4)));
typedef unsigned short u16x8 __attribute__((ext_vector_type(8)));

#define T_STEPS 512
#define NBLK 64
#define FINAL_OFF 33554432u  // 512*64*1024

// ---------------- workspace layout (bytes) ----------------
#define OFF_XR   0ull
#define OFF_XZ   (OFF_XR + 67108864ull)     // 512*64*1024 * 2B each
#define OFF_XH   (OFF_XZ + 67108864ull)
#define OFF_WXRT (OFF_XH + 67108864ull)     // 1024*1024*2B each
#define OFF_WXZT (OFF_WXRT + 2097152ull)
#define OFF_WXHT (OFF_WXZT + 2097152ull)
#define OFF_WHRT (OFF_WXHT + 2097152ull)
#define OFF_WHZT (OFF_WHRT + 2097152ull)
#define OFF_WHHT (OFF_WHZT + 2097152ull)
#define OFF_HBF  (OFF_WHHT + 2097152ull)    // 64*1024 bf16, TILE-BLOCKED (coherent)
#define OFF_RHBF (OFF_HBF + 131072ull)      // 64*1024 bf16, TILE-BLOCKED (coherent)
#define OFF_HF32 (OFF_RHBF + 131072ull)     // (unused this version)
#define OFF_BAR  (OFF_HF32 + 262144ull)     // 256 per-wave flags, 128B apart (r6 layout)
#define BAR_BYTES 65600ull

// ---------------- helpers ----------------
__device__ __forceinline__ u16 f2bf(float f) {
    unsigned u = __builtin_bit_cast(unsigned, f);
    unsigned r = (u + 0x7FFFu + ((u >> 16) & 1u)) >> 16;
    return (u16)r;
}
__device__ __forceinline__ float bf2f(u16 h) {
    unsigned u = ((unsigned)h) << 16;
    return __builtin_bit_cast(float, u);
}
#define MFMA16 __builtin_amdgcn_mfma_f32_16x16x32_bf16

// coherent (agent-scope) atomic accesses: flags + cross-block data stores.
__device__ __forceinline__ void sta16(u16* p, u16 v) {
    __hip_atomic_store(p, v, __ATOMIC_RELAXED, __HIP_MEMORY_SCOPE_AGENT);
}
__device__ __forceinline__ void sta32(unsigned* p, unsigned v) {
    __hip_atomic_store(p, v, __ATOMIC_RELAXED, __HIP_MEMORY_SCOPE_AGENT);
}
__device__ __forceinline__ unsigned lda32(const unsigned* p) {
    return __hip_atomic_load(p, __ATOMIC_RELAXED, __HIP_MEMORY_SCOPE_AGENT);
}

// Raw coherent 16B load (sc0|sc1): same visibility as relaxed agent atomic,
// fire-and-forget issue; completion claimed by explicit vmcnt(0)+sched_barrier.
#define LD_A4(dst, vo, base)                                          \
    asm volatile("global_load_dwordx4 %0, %1, %2 sc0 sc1"             \
                 : "=v"(dst) : "v"(vo), "s"(base))

#define FLAG_STRIDE 32u  // 32 u32 = 128 bytes per flag (round-6 layout: private line per writer)

// ---------------- phase 0: transpose + fp32->bf16 convert, [K][N] -> [N][K] ----------------
__global__ __launch_bounds__(256) void transpose_cvt(
    const float* __restrict__ W0, const float* __restrict__ W1, const float* __restrict__ W2,
    const float* __restrict__ W3, const float* __restrict__ W4, const float* __restrict__ W5,
    u16* __restrict__ D0, u16* __restrict__ D1, u16* __restrict__ D2,
    u16* __restrict__ D3, u16* __restrict__ D4, u16* __restrict__ D5)
{
    const float* S[6] = {W0, W1, W2, W3, W4, W5};
    u16* D[6] = {D0, D1, D2, D3, D4, D5};
    int z = blockIdx.z;
    const float* W = S[z];
    u16* Dt = D[z];
    __shared__ float tile[32][33];
    int bx = blockIdx.x * 32, by = blockIdx.y * 32;
    int tx = threadIdx.x & 31, ty = threadIdx.x >> 5;
    for (int i = ty; i < 32; i += 8)
        tile[i][tx] = W[(size_t)(by + i) * 1024 + bx + tx];
    __syncthreads();
    for (int i = ty; i < 32; i += 8)
        Dt[(size_t)(bx + i) * 1024 + by + tx] = f2bf(tile[tx][i]);
}

// ---------------- phase 1: X @ Wx* + b -> bf16 projections ----------------
__global__ __launch_bounds__(256, 2) void proj_gemm(
    const float* __restrict__ X,
    const u16* __restrict__ Wt0, const u16* __restrict__ Wt1, const u16* __restrict__ Wt2,
    const float* __restrict__ b0, const float* __restrict__ b1, const float* __restrict__ b2,
    u16* __restrict__ P0, u16* __restrict__ P1, u16* __restrict__ P2)
{
    int z = blockIdx.z;
    const u16* Wt = (z == 0) ? Wt0 : (z == 1) ? Wt1 : Wt2;
    const float* bias = (z == 0) ? b0 : (z == 1) ? b1 : b2;
    u16* P = (z == 0) ? P0 : (z == 1) ? P1 : P2;

    __shared__ u16 Asm[128][72];
    __shared__ u16 Bsm[128][72];

    int tid = threadIdx.x, lane = tid & 63, w = tid >> 6;
    int m0 = blockIdx.y * 128, n0 = blockIdx.x * 128;
    int mw = (w >> 1) * 64, nw = (w & 1) * 64;
    int l15 = lane & 15, lq = lane >> 4;

    f32x4 zero = {0.f, 0.f, 0.f, 0.f};
    f32x4 acc[4][4];
    #pragma unroll
    for (int mi = 0; mi < 4; ++mi)
        #pragma unroll
        for (int nj = 0; nj < 4; ++nj) acc[mi][nj] = zero;

    for (int k0 = 0; k0 < 1024; k0 += 64) {
        #pragma unroll
        for (int i = 0; i < 8; ++i) {
            int flat = i * 256 + tid;
            int r = flat >> 4, c4 = flat & 15;
            float4 v = *(const float4*)(X + (size_t)(m0 + r) * 1024 + k0 + c4 * 4);
            u16x4 pk = {f2bf(v.x), f2bf(v.y), f2bf(v.z), f2bf(v.w)};
            *(u16x4*)&Asm[r][c4 * 4] = pk;
        }
        #pragma unroll
        for (int i = 0; i < 4; ++i) {
            int flat = i * 256 + tid;
            int n = flat >> 3, seg = flat & 7;
            *(u16x8*)&Bsm[n][seg * 8] = *(const u16x8*)(Wt + (size_t)(n0 + n) * 1024 + k0 + seg * 8);
        }
        __syncthreads();
        #pragma unroll
        for (int kk = 0; kk < 2; ++kk) {
            bf16x8 af[4], bg[4];
            #pragma unroll
            for (int mi = 0; mi < 4; ++mi)
                af[mi] = *(const bf16x8*)&Asm[mw + mi * 16 + l15][kk * 32 + lq * 8];
            #pragma unroll
            for (int nj = 0; nj < 4; ++nj)
                bg[nj] = *(const bf16x8*)&Bsm[nw + nj * 16 + l15][kk * 32 + lq * 8];
            #pragma unroll
            for (int mi = 0; mi < 4; ++mi)
                #pragma unroll
                for (int nj = 0; nj < 4; ++nj)
                    acc[mi][nj] = MFMA16(af[mi], bg[nj], acc[mi][nj], 0, 0, 0);
        }
        __syncthreads();
    }
    #pragma unroll
    for (int mi = 0; mi < 4; ++mi)
        #pragma unroll
        for (int nj = 0; nj < 4; ++nj)
            #pragma unroll
            for (int r = 0; r < 4; ++r) {
                int m = m0 + mw + mi * 16 + lq * 4 + r;
                int n = n0 + nw + nj * 16 + l15;
                float v = acc[mi][nj][r] + bias[n];
                P[(size_t)m * 1024 + n] = f2bf(v);
            }
}

// ---------------- phase 2: persistent recurrent kernel, PER-WAVE dataflow ----------------
// Identical protocol/flags to round 6 (128B-strided per-wave flags -- private
// line per writer; r7 proved same-line writer packing costs +25%). SINGLE
// CHANGE vs r6: hbf/rhbf are TILE-BLOCKED. tile(mi,b) = rows [16mi,16mi+16) x
// cols [16b,16b+16), stored row-major in 512 CONTIGUOUS bytes at
// (mi*64+b)*512. Producer wave (b,mi) writes exactly its own tile: 4 cache
// lines (was 16 scattered). Consumer k-pair kb reads tiles 2kb,2kb+1: one
// LD_A4 spans 1KB contiguous = 8 lines (was 16 rows x 64B windows 2KB apart).
// Halves coherence-point line-transactions for the h/R*h exchange.
// Protocol: init->1; stage1(t)->2t+2; stage2(t)->2t+3; stage1 consumes hbf
// gated >=2t+1; stage2 consumes rhbf gated >=2t+2; per-wave vmcnt(0) drain
// before every publish (release; WAR-safe on single-buffered hbf/rhbf).
__global__ __launch_bounds__(256, 1) void gru_rec(
    const u16* __restrict__ XR, const u16* __restrict__ XZ, const u16* __restrict__ XH,
    const u16* __restrict__ Whrt, const u16* __restrict__ Whzt, const u16* __restrict__ Whht,
    const float* __restrict__ state,
    u16* __restrict__ hbf, u16* __restrict__ rhbf,
    unsigned* __restrict__ bar, float* __restrict__ out)
{
    __shared__ u16 Wsm[48 * 1024];  // rows 0-15 Whr, 16-31 Whz, 32-47 Whh (96 KB)

    const int b = blockIdx.x, tid = threadIdx.x;
    const int lane = tid & 63, mi = tid >> 6;
    const int n15 = lane & 15, q = lane >> 4;
    const int k7 = n15 & 7;
    const int colg = 16 * b + n15;
    const int rot = (((b >> 1) + ((b & 1) << 4)) + mi * 8) & 31;  // per-wave start pair
    const u64 own_bit = 1ull << b;

    // fill LDS weight slices (swizzled 16B chunks: phys = chunk ^ (row&7))
    {
        int r0 = tid >> 3, seg = tid & 7;
        #pragma unroll
        for (int pass = 0; pass < 2; ++pass) {
            int row = pass * 32 + r0;
            if (row < 48) {
                const u16* src = (row < 16) ? (Whrt + (size_t)(16 * b + row) * 1024)
                               : (row < 32) ? (Whzt + (size_t)(16 * b + row - 16) * 1024)
                                            : (Whht + (size_t)(16 * b + row - 32) * 1024);
                #pragma unroll
                for (int v = 0; v < 16; ++v) {
                    int chunk = seg * 16 + v;
                    int phys = chunk ^ (row & 7);
                    *(u16x8*)&Wsm[row * 1024 + phys * 8] = *(const u16x8*)(src + chunk * 8);
                }
            }
        }
    }
    // own tile base (u16 units): tile(mi,b) at (mi*64+b)*256
    const unsigned tbase = (unsigned)((mi * 64 + b) * 256);
    // init h: each wave fills its own 512B tile from state (row-major source)
    f32x4 hcar;
    #pragma unroll
    for (int r = 0; r < 4; ++r) {
        int row = mi * 16 + q * 4 + r;
        float v = state[row * 1024 + colg];
        hcar[r] = v;
        sta16(hbf + tbase + (q * 4 + r) * 16 + n15, f2bf(v));
    }
    // publish init (flag = 1), per-wave; then one barrier for Wsm visibility
    asm volatile("s_waitcnt vmcnt(0)" ::: "memory");
    if (lane == 0) sta32(bar + (unsigned)((b << 2) | mi) * FLAG_STRIDE, 1u);
    __syncthreads();  // Wsm ready for all 4 waves; last sync in the kernel

    const u64 hb64 = (u64)hbf;
    const u64 rb64 = (u64)rhbf;
    // A-fragment byte base in tile space: wave-stripe mi starts at mi*64
    // tiles * 512B; lane reads tile 2kb+(q>>1), row n15, col-octet (q&1).
    const unsigned vbA = (unsigned)(mi * 32768 + (q >> 1) * 512 + n15 * 32 + (q & 1) * 16);
    // lane l -> block l's wave-mi flag (r6 layout: 128B stride)
    const unsigned* fp = bar + (unsigned)((lane << 2) | mi) * FLAG_STRIDE;
    unsigned* myflag = bar + (unsigned)((b << 2) | mi) * FLAG_STRIDE;

    for (int t = 0; t < T_STEPS; ++t) {
        f32x4 zreg;
        // ---------------- stage 1: R,Z; write rhbf = R*h ----------------
        {
            u16 xr16[4], xz16[4];
            #pragma unroll
            for (int r = 0; r < 4; ++r) {
                size_t xoff = (size_t)t * 65536 + (mi * 16 + q * 4 + r) * 1024 + colg;
                xr16[r] = XR[xoff];
                xz16[r] = XZ[xoff];
            }
            // dataflow consume: issue A-load for each k-pair as its producers arrive
            f32x4 a[32];
            const unsigned T1 = 2u * t + 1u;
            u64 rdy = __ballot(lda32(fp) >= T1) | own_bit;  // fast path: one gather
            #pragma unroll
            for (int i = 0; i < 32; ++i) {
                int kb = (i + rot) & 31;
                u64 need = 3ull << (2 * kb);
                while ((rdy & need) != need) {
                    __builtin_amdgcn_s_sleep(1);
                    rdy = __ballot(lda32(fp) >= T1) | own_bit;
                }
                LD_A4(a[i], vbA + kb * 1024, hb64);
            }
            asm volatile("s_waitcnt vmcnt(0)" ::: "memory");
            __builtin_amdgcn_sched_barrier(0);

            f32x4 aRa = {0,0,0,0}, aRb = {0,0,0,0}, aZa = {0,0,0,0}, aZb = {0,0,0,0};
            #pragma unroll
            for (int i = 0; i < 32; ++i) {
                int kb = (i + rot) & 31;
                bf16x8 av = __builtin_bit_cast(bf16x8, a[i]);
                int ph = ((kb * 4 + q) ^ k7) * 8;
                bf16x8 br = *(const bf16x8*)&Wsm[n15 * 1024 + ph];
                bf16x8 bz = *(const bf16x8*)&Wsm[(16 + n15) * 1024 + ph];
                if (i & 1) { aRb = MFMA16(av, br, aRb, 0, 0, 0); aZb = MFMA16(av, bz, aZb, 0, 0, 0); }
                else       { aRa = MFMA16(av, br, aRa, 0, 0, 0); aZa = MFMA16(av, bz, aZa, 0, 0, 0); }
            }
            f32x4 accR = aRa + aRb, accZ = aZa + aZb;
            #pragma unroll
            for (int r = 0; r < 4; ++r) {
                float rpre = accR[r] + bf2f(xr16[r]);
                float zpre = accZ[r] + bf2f(xz16[r]);
                float R = 1.f / (1.f + __expf(-rpre));
                zreg[r] = 1.f / (1.f + __expf(-zpre));
                sta16(rhbf + tbase + (q * 4 + r) * 16 + n15, f2bf(R * hcar[r]));
            }
            // publish stage 1 (flag = 2t+2): per-wave drain + own flag store
            asm volatile("s_waitcnt vmcnt(0)" ::: "memory");
            if (lane == 0) sta32(myflag, 2u * t + 2u);
        }
        // ---------------- stage 2: Hhat = tanh(Xh + (R*h)@Whh); blend ----------------
        {
            u16 xh16[4];
            #pragma unroll
            for (int r = 0; r < 4; ++r) {
                size_t xoff = (size_t)t * 65536 + (mi * 16 + q * 4 + r) * 1024 + colg;
                xh16[r] = XH[xoff];
            }
            f32x4 a[32];
            const unsigned T2 = 2u * t + 2u;
            u64 rdy = __ballot(lda32(fp) >= T2) | own_bit;  // fast path: one gather
            #pragma unroll
            for (int i = 0; i < 32; ++i) {
                int kb = (i + rot) & 31;
                u64 need = 3ull << (2 * kb);
                while ((rdy & need) != need) {
                    __builtin_amdgcn_s_sleep(1);
                    rdy = __ballot(lda32(fp) >= T2) | own_bit;
                }
                LD_A4(a[i], vbA + kb * 1024, rb64);
            }
            asm volatile("s_waitcnt vmcnt(0)" ::: "memory");
            __builtin_amdgcn_sched_barrier(0);

            f32x4 ca = {0,0,0,0}, cb = {0,0,0,0};
            #pragma unroll
            for (int i = 0; i < 32; ++i) {
                int kb = (i + rot) & 31;
                bf16x8 av = __builtin_bit_cast(bf16x8, a[i]);
                int ph = ((kb * 4 + q) ^ k7) * 8;
                bf16x8 bh = *(const bf16x8*)&Wsm[(32 + n15) * 1024 + ph];
                if (i & 1) cb = MFMA16(av, bh, cb, 0, 0, 0);
                else       ca = MFMA16(av, bh, ca, 0, 0, 0);
            }
            f32x4 acc = ca + cb;
            float hn4[4];
            #pragma unroll
            for (int r = 0; r < 4; ++r) {
                float pre = acc[r] + bf2f(xh16[r]);
                float ax = fabsf(pre);
                float e = __expf(-2.f * ax);
                float th = (1.f - e) / (1.f + e);
                float hh = (pre < 0.f) ? -th : th;
                float hn = zreg[r] * hcar[r] + (1.f - zreg[r]) * hh;
                hn4[r] = hn;
                hcar[r] = hn;
                sta16(hbf + tbase + (q * 4 + r) * 16 + n15, f2bf(hn));  // shared tile
            }
            if (t != T_STEPS - 1) {
                // publish stage 2 (flag = 2t+3) BEFORE the out stores (out is
                // write-once, consumed only at kernel end; keeps HBM stores
                // off the publish critical path)
                asm volatile("s_waitcnt vmcnt(0)" ::: "memory");
                if (lane == 0) sta32(myflag, 2u * t + 3u);
            }
            #pragma unroll
            for (int r = 0; r < 4; ++r) {
                int idx = (mi * 16 + q * 4 + r) * 1024 + colg;
                size_t xoff = (size_t)t * 65536 + idx;
                out[xoff] = hn4[r];
                if (t == T_STEPS - 1) out[FINAL_OFF + idx] = hn4[r];
            }
        }
    }
}

// ---------------- launch ----------------
extern "C" void kernel_launch(void* const* d_in, const int* in_sizes, int n_in,
                              void* d_out, int out_size, void* d_ws, size_t ws_size,
                              hipStream_t stream) {
    (void)in_sizes; (void)n_in; (void)out_size; (void)ws_size;
    const float* X     = (const float*)d_in[0];
    const float* state = (const float*)d_in[1];
    const float* Wxr   = (const float*)d_in[2];
    const float* Whr   = (const float*)d_in[3];
    const float* br    = (const float*)d_in[4];
    const float* Wxz   = (const float*)d_in[5];
    const float* Whz   = (const float*)d_in[6];
    const float* bz    = (const float*)d_in[7];
    const float* Wxh   = (const float*)d_in[8];
    const float* Whh   = (const float*)d_in[9];
    const float* bh    = (const float*)d_in[10];
    float* out = (float*)d_out;
    char* ws = (char*)d_ws;

    u16* XR   = (u16*)(ws + OFF_XR);
    u16* XZ   = (u16*)(ws + OFF_XZ);
    u16* XH   = (u16*)(ws + OFF_XH);
    u16* WXRT = (u16*)(ws + OFF_WXRT);
    u16* WXZT = (u16*)(ws + OFF_WXZT);
    u16* WXHT = (u16*)(ws + OFF_WXHT);
    u16* WHRT = (u16*)(ws + OFF_WHRT);
    u16* WHZT = (u16*)(ws + OFF_WHZT);
    u16* WHHT = (u16*)(ws + OFF_WHHT);
    u16* HBF  = (u16*)(ws + OFF_HBF);
    u16* RHBF = (u16*)(ws + OFF_RHBF);
    unsigned* BAR = (unsigned*)(ws + OFF_BAR);

    hipMemsetAsync(BAR, 0, BAR_BYTES, stream);

    transpose_cvt<<<dim3(32, 32, 6), 256, 0, stream>>>(
        Wxr, Wxz, Wxh, Whr, Whz, Whh,
        WXRT, WXZT, WXHT, WHRT, WHZT, WHHT);

    proj_gemm<<<dim3(8, 256, 3), 256, 0, stream>>>(
        X, WXRT, WXZT, WXHT, br, bz, bh, XR, XZ, XH);

    gru_rec<<<dim3(NBLK), 256, 0, stream>>>(
        XR, XZ, XH, WHRT, WHZT, WHHT, state,
        HBF, RHBF, BAR, out);
}